// Round 3
// 1088.495 us; speedup vs baseline: 1.0780x; 1.0780x over previous
//
#include <hip/hip_runtime.h>
#include <hip/hip_bf16.h>

#define E_DIM 512
#define H_DIM 1024
#define V_DIM 50257
#define B_DIM 64
#define S_DIM 2048

typedef unsigned short ushort_t;
typedef __attribute__((ext_vector_type(8))) short bf16x8;
typedef __attribute__((ext_vector_type(4))) float f32x4;

__device__ __forceinline__ ushort_t f2b(float f) {
    __hip_bfloat16 h = __float2bfloat16(f);  // RNE
    ushort_t u;
    __builtin_memcpy(&u, &h, 2);
    return u;
}
__device__ __forceinline__ float dot4(float4 a, float4 b) {
    return a.x * b.x + a.y * b.y + a.z * b.z + a.w * b.w;
}

// ---------------- Kernel 1: GRU cell (f32) ----------------
// thread per (b, jh); wave lanes span b -> weight rows wave-uniform (broadcast)
__global__ __launch_bounds__(256) void k_gru(
    const float* __restrict__ x,    // [B,E]
    const float* __restrict__ h,    // [B,H]
    const float* __restrict__ w_ih, // [3H,E]
    const float* __restrict__ w_hh, // [3H,H]
    const float* __restrict__ b_ih, // [3H]
    const float* __restrict__ b_hh, // [3H]
    float* __restrict__ ws_hnew,    // [B,H]
    float* __restrict__ out_hidden) // [B,H]
{
    int g = blockIdx.x * 256 + threadIdx.x;
    int b = g & 63;
    int jh = g >> 6;
    const float4* x4 = (const float4*)(x + b * E_DIM);
    const float4* h4 = (const float4*)(h + b * H_DIM);
    const float4* wr_i = (const float4*)(w_ih + (size_t)jh * E_DIM);
    const float4* wz_i = (const float4*)(w_ih + (size_t)(jh + H_DIM) * E_DIM);
    const float4* wn_i = (const float4*)(w_ih + (size_t)(jh + 2 * H_DIM) * E_DIM);
    const float4* wr_h = (const float4*)(w_hh + (size_t)jh * H_DIM);
    const float4* wz_h = (const float4*)(w_hh + (size_t)(jh + H_DIM) * H_DIM);
    const float4* wn_h = (const float4*)(w_hh + (size_t)(jh + 2 * H_DIM) * H_DIM);

    float gir = 0.f, giz = 0.f, gin = 0.f;
    for (int e4 = 0; e4 < E_DIM / 4; ++e4) {
        float4 xv = x4[e4];
        gir += dot4(xv, wr_i[e4]);
        giz += dot4(xv, wz_i[e4]);
        gin += dot4(xv, wn_i[e4]);
    }
    float ghr = 0.f, ghz = 0.f, ghn = 0.f;
    for (int k4 = 0; k4 < H_DIM / 4; ++k4) {
        float4 hv = h4[k4];
        ghr += dot4(hv, wr_h[k4]);
        ghz += dot4(hv, wz_h[k4]);
        ghn += dot4(hv, wn_h[k4]);
    }
    gir += b_ih[jh];             ghr += b_hh[jh];
    giz += b_ih[jh + H_DIM];     ghz += b_hh[jh + H_DIM];
    gin += b_ih[jh + 2 * H_DIM]; ghn += b_hh[jh + 2 * H_DIM];

    float r = 1.f / (1.f + expf(-(gir + ghr)));
    float z = 1.f / (1.f + expf(-(giz + ghz)));
    float n = tanhf(gin + r * ghn);
    float hprev = h[b * H_DIM + jh];
    float hnew = (1.f - z) * n + z * hprev;
    ws_hnew[b * H_DIM + jh] = hnew;
    out_hidden[b * H_DIM + jh] = hnew;
}

// ---------------- Kernel 2: fused attention, single enc pass ----------------
// Flash-style. Block per (b, chunk of 128 s); each of 4 waves handles 32 s.
// Each enc row is loaded ONCE into registers, used for both the energy dot and
// the online-softmax-weighted context accumulation. The 4 waves' (m,l,ctx[H])
// are combined in LDS so the workspace partial is [B,16,H] (4 MB).
__global__ __launch_bounds__(256) void k_attn(
    const float* __restrict__ enc,   // [S,B,H]
    const float* __restrict__ hnew,  // [B,H]
    float* __restrict__ e_out,       // [B,S] raw energies
    float* __restrict__ mpart,       // [B,16]
    float* __restrict__ lpart,       // [B,16]
    float* __restrict__ ctxpart)     // [B,16,H]
{
    int b = blockIdx.x >> 4;
    int c = blockIdx.x & 15;
    int w = threadIdx.x >> 6;
    int lane = threadIdx.x & 63;
    int s0 = c * 128 + w * 32;

    const float4* hv = (const float4*)(hnew + b * H_DIM + lane * 16);
    float4 h0 = hv[0], h1 = hv[1], h2 = hv[2], h3 = hv[3];

    const size_t sstride = (size_t)B_DIM * H_DIM;  // floats between consecutive s
    const float* p = enc + ((size_t)s0 * B_DIM + b) * H_DIM + lane * 16;

    float4 a0 = {0.f, 0.f, 0.f, 0.f}, a1 = a0, a2 = a0, a3 = a0;
    float m = -3.0e38f, l = 0.f;

    float4 v0 = ((const float4*)p)[0];
    float4 v1 = ((const float4*)p)[1];
    float4 v2 = ((const float4*)p)[2];
    float4 v3 = ((const float4*)p)[3];

    for (int it = 0; it < 32; ++it) {
        // software prefetch of next s so HBM latency hides under the reduce/update
        float4 n0, n1, n2, n3;
        const float* pn = p + sstride;
        if (it < 31) {
            n0 = ((const float4*)pn)[0];
            n1 = ((const float4*)pn)[1];
            n2 = ((const float4*)pn)[2];
            n3 = ((const float4*)pn)[3];
        }
        float e = dot4(v0, h0) + dot4(v1, h1) + dot4(v2, h2) + dot4(v3, h3);
        #pragma unroll
        for (int off = 32; off; off >>= 1) e += __shfl_xor(e, off, 64);
        if (lane == 0) e_out[b * S_DIM + s0 + it] = e;
        if (e > m) {  // wave-uniform branch (e uniform after full butterfly)
            float sc = __expf(m - e);   // first iter: exp(-inf-ish) = 0, state already 0
            l *= sc;
            a0.x *= sc; a0.y *= sc; a0.z *= sc; a0.w *= sc;
            a1.x *= sc; a1.y *= sc; a1.z *= sc; a1.w *= sc;
            a2.x *= sc; a2.y *= sc; a2.z *= sc; a2.w *= sc;
            a3.x *= sc; a3.y *= sc; a3.z *= sc; a3.w *= sc;
            m = e;
        }
        float pw = __expf(e - m);
        l += pw;
        a0.x += pw * v0.x; a0.y += pw * v0.y; a0.z += pw * v0.z; a0.w += pw * v0.w;
        a1.x += pw * v1.x; a1.y += pw * v1.y; a1.z += pw * v1.z; a1.w += pw * v1.w;
        a2.x += pw * v2.x; a2.y += pw * v2.y; a2.z += pw * v2.z; a2.w += pw * v2.w;
        a3.x += pw * v3.x; a3.y += pw * v3.y; a3.z += pw * v3.z; a3.w += pw * v3.w;
        if (it < 31) {
            p = pn;
            v0 = n0; v1 = n1; v2 = n2; v3 = n3;
        }
    }

    // ---- combine the 4 waves' (m, l, a[·]) in LDS ----
    __shared__ float sa[4][H_DIM];   // 16 KB
    __shared__ float sml[8];         // m[4], l[4]
    float* dst = &sa[w][lane * 16];
    ((float4*)dst)[0] = a0; ((float4*)dst)[1] = a1;
    ((float4*)dst)[2] = a2; ((float4*)dst)[3] = a3;
    if (lane == 0) { sml[w] = m; sml[4 + w] = l; }
    __syncthreads();

    float M = fmaxf(fmaxf(sml[0], sml[1]), fmaxf(sml[2], sml[3]));
    float sc0 = __expf(sml[0] - M), sc1 = __expf(sml[1] - M);
    float sc2 = __expf(sml[2] - M), sc3 = __expf(sml[3] - M);
    int t = threadIdx.x;  // thread t owns h = t*4 .. t*4+3
    float4 r0 = ((const float4*)&sa[0][0])[t];
    float4 r1 = ((const float4*)&sa[1][0])[t];
    float4 r2 = ((const float4*)&sa[2][0])[t];
    float4 r3 = ((const float4*)&sa[3][0])[t];
    float4 r;
    r.x = sc0 * r0.x + sc1 * r1.x + sc2 * r2.x + sc3 * r3.x;
    r.y = sc0 * r0.y + sc1 * r1.y + sc2 * r2.y + sc3 * r3.y;
    r.z = sc0 * r0.z + sc1 * r1.z + sc2 * r2.z + sc3 * r3.z;
    r.w = sc0 * r0.w + sc1 * r1.w + sc2 * r2.w + sc3 * r3.w;
    ((float4*)(ctxpart + (size_t)(b * 16 + c) * H_DIM))[t] = r;
    if (t == 0) {
        float Lc = sc0 * sml[4] + sc1 * sml[5] + sc2 * sml[6] + sc3 * sml[7];
        mpart[b * 16 + c] = M;
        lpart[b * 16 + c] = Lc;
    }
}

// ---------------- Kernel 3: combine partials + attn weights ----------------
// block per (b, quarter q). Exact combine:
//   L = sum_c l_c * exp(m_c - M);  ctx = sum_c exp(m_c - M) * ctxpart_c / L
//   attn[b,s] = exp(e_s - M) / L
// ctx is written IN PLACE into ctxpart chunk 0 of each batch (each thread
// overwrites exactly the slot it already read; blocks touch disjoint slices).
__global__ __launch_bounds__(256) void k_finish(
    const float* __restrict__ e_in,   // [B,S]
    const float* __restrict__ mpart,  // [B,16]
    const float* __restrict__ lpart,  // [B,16]
    float* ctxpart,                   // [B,16,H] in; chunk0 out = ctx (no restrict: r/w alias)
    float* __restrict__ out_attn)     // [B,1,S]
{
    int b = blockIdx.x >> 2, q = blockIdx.x & 3;
    int t = threadIdx.x, lane = t & 63, wid = t >> 6;
    __shared__ float sSc[16];
    __shared__ float sM, sInvL;
    if (wid == 0) {
        float mc = (lane < 16) ? mpart[b * 16 + lane] : -3.0e38f;
        float lc = (lane < 16) ? lpart[b * 16 + lane] : 0.f;
        float M = mc;
        #pragma unroll
        for (int off = 32; off; off >>= 1) M = fmaxf(M, __shfl_xor(M, off, 64));
        float sc = (lane < 16) ? __expf(mc - M) : 0.f;
        if (lane < 16) sSc[lane] = sc;
        float L = lc * sc;
        #pragma unroll
        for (int off = 32; off; off >>= 1) L += __shfl_xor(L, off, 64);
        if (lane == 0) { sM = M; sInvL = 1.f / L; }
    }
    __syncthreads();
    float M = sM, invL = sInvL;
    // context slice: h = q*256 + t (coalesced: consecutive t -> consecutive addr)
    float* cp = ctxpart + (size_t)b * 16 * H_DIM + q * 256 + t;
    float a = 0.f;
    #pragma unroll
    for (int c0 = 0; c0 < 16; ++c0) a += sSc[c0] * cp[(size_t)c0 * H_DIM];
    cp[0] = a * invL;  // in-place: chunk 0 slot, read above at c0=0
    // attention weights slice: s in [q*512, q*512+512)
    const float* eb = e_in + b * S_DIM + q * 512;
    float* ab = out_attn + b * S_DIM + q * 512;
    ab[t]       = __expf(eb[t]       - M) * invL;
    ab[t + 256] = __expf(eb[t + 256] - M) * invL;
}

// ---------------- Kernel 4: concat projection (f32 -> bf16 X) ----------------
// ctx is read from ctxpart chunk 0: stride 16*H per batch.
__global__ __launch_bounds__(256) void k_concat(
    const float* __restrict__ hnew,
    const float* __restrict__ ctx16, // [B,16,H], chunk 0 = ctx
    const float* __restrict__ Wc,    // [H, 2H]
    const float* __restrict__ bc,    // [H]
    ushort_t* __restrict__ Xb)       // [B,H] bf16 (MFMA B-operand)
{
    int g = blockIdx.x * 256 + threadIdx.x;
    int b = g & 63, jo = g >> 6;
    const float4* w1 = (const float4*)(Wc + (size_t)jo * 2 * H_DIM);
    const float4* w2 = (const float4*)(Wc + (size_t)jo * 2 * H_DIM + H_DIM);
    const float4* hv = (const float4*)(hnew + b * H_DIM);
    const float4* cv = (const float4*)(ctx16 + (size_t)b * 16 * H_DIM);
    float acc = bc[jo];
    for (int k4 = 0; k4 < H_DIM / 4; ++k4) {
        acc += dot4(hv[k4], w1[k4]);
        acc += dot4(cv[k4], w2[k4]);
    }
    Xb[b * H_DIM + jo] = f2b(tanhf(acc));
}

// ---------------- Kernel 5: vocab projection (MFMA, f32 W_out cast inline) ----------------
__global__ __launch_bounds__(256) void k_out(
    const float* __restrict__ Wout,  // [V,H] f32
    const ushort_t* __restrict__ Xb, // [B,H] bf16
    const float* __restrict__ bout,  // [V] f32
    float* __restrict__ out)         // [B,V] f32
{
    int wave = (blockIdx.x * 256 + threadIdx.x) >> 6;
    int lane = threadIdx.x & 63;
    int v0 = wave * 16;
    if (v0 >= V_DIM) return;
    int m = lane & 15, quad = lane >> 4;
    int arow = v0 + m;
    if (arow > V_DIM - 1) arow = V_DIM - 1;
    const float* wr = Wout + (size_t)arow * H_DIM + quad * 8;
    const short* xrow = (const short*)Xb + m * H_DIM + quad * 8;

    f32x4 acc[4] = {{0.f, 0.f, 0.f, 0.f}, {0.f, 0.f, 0.f, 0.f},
                    {0.f, 0.f, 0.f, 0.f}, {0.f, 0.f, 0.f, 0.f}};
    for (int k0 = 0; k0 < H_DIM; k0 += 32) {
        float4 a0 = *(const float4*)(wr + k0);
        float4 a1 = *(const float4*)(wr + k0 + 4);
        bf16x8 a;
        a[0] = (short)f2b(a0.x); a[1] = (short)f2b(a0.y);
        a[2] = (short)f2b(a0.z); a[3] = (short)f2b(a0.w);
        a[4] = (short)f2b(a1.x); a[5] = (short)f2b(a1.y);
        a[6] = (short)f2b(a1.z); a[7] = (short)f2b(a1.w);
        #pragma unroll
        for (int bt = 0; bt < 4; ++bt) {
            bf16x8 bb = *(const bf16x8*)(xrow + bt * 16 * H_DIM + k0);
            acc[bt] = __builtin_amdgcn_mfma_f32_16x16x32_bf16(a, bb, acc[bt], 0, 0, 0);
        }
    }
    // C/D layout (m89-verified): col(n=b-local)=lane&15, row(m=v-local)=quad*4+reg
    #pragma unroll
    for (int bt = 0; bt < 4; ++bt) {
        int b = bt * 16 + m;
        #pragma unroll
        for (int r = 0; r < 4; ++r) {
            int v = v0 + quad * 4 + r;
            if (v < V_DIM) out[(size_t)b * V_DIM + v] = acc[bt][r] + bout[v];
        }
    }
}

extern "C" void kernel_launch(void* const* d_in, const int* in_sizes, int n_in,
                              void* d_out, int out_size, void* d_ws, size_t ws_size,
                              hipStream_t stream) {
    const float* x    = (const float*)d_in[0];
    const float* h    = (const float*)d_in[1];
    const float* enc  = (const float*)d_in[2];
    const float* w_ih = (const float*)d_in[3];
    const float* w_hh = (const float*)d_in[4];
    const float* b_ih = (const float*)d_in[5];
    const float* b_hh = (const float*)d_in[6];
    const float* Wc   = (const float*)d_in[7];
    const float* bc   = (const float*)d_in[8];
    const float* Wout = (const float*)d_in[9];
    const float* bout = (const float*)d_in[10];

    float* out        = (float*)d_out;
    float* out_hidden = out + (size_t)B_DIM * V_DIM;
    float* out_attn   = out_hidden + B_DIM * H_DIM;

    // ws layout: 5000 KB total — safely under the 5.125 MB (5248 KB) cap the
    // baseline established. ctx has no separate buffer: it lives in ctxpart
    // chunk 0 per batch after k_finish.
    char* ws = (char*)d_ws;
    float* ws_hnew    = (float*)ws;                      // 256 KB [B,H]
    float* ws_e       = (float*)(ws + (256 << 10));      // 512 KB [B,S] raw energies
    float* ws_m       = (float*)(ws + (768 << 10));      // 4 KB   [B,16]
    float* ws_l       = (float*)(ws + (772 << 10));      // 4 KB   [B,16]
    ushort_t* ws_Xb   = (ushort_t*)(ws + (776 << 10));   // 128 KB [B,H] bf16
    float* ws_ctxpart = (float*)(ws + (904 << 10));      // 4 MB   [B,16,H] -> ends 5000 KB

    k_gru<<<B_DIM * H_DIM / 256, 256, 0, stream>>>(x, h, w_ih, w_hh, b_ih, b_hh,
                                                   ws_hnew, out_hidden);
    k_attn<<<B_DIM * 16, 256, 0, stream>>>(enc, ws_hnew, ws_e, ws_m, ws_l,
                                           ws_ctxpart);
    k_finish<<<B_DIM * 4, 256, 0, stream>>>(ws_e, ws_m, ws_l, ws_ctxpart, out_attn);
    k_concat<<<B_DIM * H_DIM / 256, 256, 0, stream>>>(ws_hnew, ws_ctxpart, Wc, bc,
                                                      ws_Xb);
    int waves4 = (V_DIM + 15) / 16;
    k_out<<<(waves4 + 3) / 4, 256, 0, stream>>>(Wout, ws_Xb, bout, out);
}